// Round 1
// baseline (1270.334 us; speedup 1.0000x reference)
//
#include <hip/hip_runtime.h>
#include <math.h>

// Problem constants (match reference)
#define B_ 4
#define N_ 4096
#define K_ 32
#define C_ 192
#define CH_ 195          // C + 3
#define LDH 36           // padded row length for s_h (multiple of 4, 16B-aligned rows)

// One block per (b, n) point. 256 threads.
// Phase A: load idx + compute dp rows (h rows 0..2)
// Phase B: gather xj, compute pe = sin/cos(50*dp/500^(f/32)), h rows 3..194 = pe*(xj+1)
// Phase C: register-tiled GEMM y[o][k] = sum_c W[o][c]*h[c][k]; BN affine per-k;
//          max over k (shfl); ReLU; store out[b][o][n].
__global__ __launch_bounds__(256) void la_kernel(
    const float* __restrict__ p,     // [B,N,3]
    const float* __restrict__ x,     // [B,C,N]
    const int*   __restrict__ idx,   // [B,N,K]
    const float* __restrict__ W,     // [C, C+3]
    const float* __restrict__ gamma_, // [C]
    const float* __restrict__ beta_,  // [C]
    const float* __restrict__ rmean, // [C]
    const float* __restrict__ rvar,  // [C]
    float* __restrict__ out)         // [B,C,N]
{
    __shared__ float s_h[CH_][LDH];
    __shared__ int   s_idx[K_];

    const int bn  = blockIdx.x;          // b*N + n
    const int b   = bn >> 12;            // / 4096
    const int n   = bn & (N_ - 1);
    const int tid = threadIdx.x;

    // ---- Phase A: neighbor ids + relative coords ----
    if (tid < K_) {
        const int j = idx[bn * K_ + tid];
        s_idx[tid] = j;
        const float px0 = p[bn * 3 + 0];
        const float px1 = p[bn * 3 + 1];
        const float px2 = p[bn * 3 + 2];
        const float* pj = p + (b * N_ + j) * 3;
        s_h[0][tid] = pj[0] - px0;
        s_h[1][tid] = pj[1] - px1;
        s_h[2][tid] = pj[2] - px2;
    }
    __syncthreads();

    // ---- Phase B: positional embedding fused with gathered features ----
    // channel c = d*64 + rem ; rem<32 -> sin(f=rem), rem>=32 -> cos(f=rem-32)
    const float L2_500_DIV_32 = 0.2801808715263400f;  // log2(500)/32
    for (int e = tid; e < C_ * K_; e += 256) {
        const int c   = e >> 5;
        const int k   = e & 31;
        const int d   = c >> 6;
        const int rem = c & 63;
        const int f   = rem & 31;
        const float invd = exp2f(-(float)f * L2_500_DIV_32);   // 500^(-f/32)
        const float ang  = 50.0f * s_h[d][k] * invd;
        const float pe   = (rem < 32) ? sinf(ang) : cosf(ang);
        const float xj   = x[(b * C_ + c) * N_ + s_idx[k]];
        s_h[3 + c][k] = pe * (xj + 1.0f);
    }
    __syncthreads();

    // ---- Phase C: GEMM + BN + ReLU + max over k ----
    // thread tile: 6 outputs (o) x 4 neighbors (k)
    const int to = tid >> 3;     // 0..31  -> o block of 6
    const int tk = tid & 7;      // 0..7   -> k block of 4
    const int o0 = to * 6;
    const int k0 = tk * 4;

    float acc[6][4];
#pragma unroll
    for (int j = 0; j < 6; ++j)
#pragma unroll
        for (int q = 0; q < 4; ++q) acc[j][q] = 0.0f;

    for (int c = 0; c < CH_; ++c) {
        const float4 h4 = *(const float4*)(&s_h[c][k0]);
#pragma unroll
        for (int j = 0; j < 6; ++j) {
            const float w = W[(o0 + j) * CH_ + c];
            acc[j][0] = fmaf(w, h4.x, acc[j][0]);
            acc[j][1] = fmaf(w, h4.y, acc[j][1]);
            acc[j][2] = fmaf(w, h4.z, acc[j][2]);
            acc[j][3] = fmaf(w, h4.w, acc[j][3]);
        }
    }

#pragma unroll
    for (int j = 0; j < 6; ++j) {
        const int o = o0 + j;
        const float inv  = gamma_[o] * rsqrtf(rvar[o] + 1e-5f);
        const float bias = beta_[o] - rmean[o] * inv;
        float m = -INFINITY;
#pragma unroll
        for (int q = 0; q < 4; ++q) {
            const float v = fmaf(acc[j][q], inv, bias);
            m = fmaxf(m, v);
        }
        // max across the 8 tk-lanes (consecutive lanes within the wave)
        m = fmaxf(m, __shfl_xor(m, 1));
        m = fmaxf(m, __shfl_xor(m, 2));
        m = fmaxf(m, __shfl_xor(m, 4));
        if (tk == 0) {
            out[(b * C_ + o) * N_ + n] = fmaxf(m, 0.0f);   // ReLU after max (monotone)
        }
    }
}

extern "C" void kernel_launch(void* const* d_in, const int* in_sizes, int n_in,
                              void* d_out, int out_size, void* d_ws, size_t ws_size,
                              hipStream_t stream) {
    const float* p      = (const float*)d_in[0];
    const float* x      = (const float*)d_in[1];
    const int*   idx    = (const int*)d_in[2];
    const float* W      = (const float*)d_in[3];
    const float* gamma_ = (const float*)d_in[4];
    const float* beta_  = (const float*)d_in[5];
    const float* rmean  = (const float*)d_in[6];
    const float* rvar   = (const float*)d_in[7];
    float* out = (float*)d_out;

    dim3 grid(B_ * N_);
    dim3 block(256);
    la_kernel<<<grid, block, 0, stream>>>(p, x, idx, W, gamma_, beta_, rmean, rvar, out);
}

// Round 2
// 554.765 us; speedup vs baseline: 2.2899x; 2.2899x over previous
//
#include <hip/hip_runtime.h>
#include <math.h>

// Problem constants
#define B_   4
#define N_   4096
#define K_   32
#define C_   192
#define CH_  195          // C + 3  (GEMM K-dim, padded to KPAD)
#define KPAD 224          // 7 x 32
#define PTS  4            // points per block
#define COLS (PTS * K_)   // 128 GEMM columns per block
#define LDH_ 232          // padded col stride in h_lds (fp16 elems): 464 B -> 2-way banks (free)

using half8 = __attribute__((ext_vector_type(8))) _Float16;
using half4 = __attribute__((ext_vector_type(4))) _Float16;
using f32x4 = __attribute__((ext_vector_type(4))) float;

// ---- per-launch W -> fp16 padded [192][224], pad cols zeroed ----
__global__ __launch_bounds__(256) void prep_w(const float* __restrict__ W,
                                              _Float16* __restrict__ Wp) {
    int i = blockIdx.x * 256 + threadIdx.x;
    if (i < C_ * KPAD) {
        int o = i / KPAD, c = i - o * KPAD;
        Wp[i] = (c < CH_) ? (_Float16)W[o * CH_ + c] : (_Float16)0.0f;
    }
}

// ---- main fused kernel: one block = 4 points, 256 threads (4 waves) ----
__global__ __launch_bounds__(256) void la_mfma(
    const float* __restrict__ p,      // [B,N,3]
    const float* __restrict__ x,      // [B,C,N]
    const int*   __restrict__ idx,    // [B,N,K]
    const _Float16* __restrict__ Wp,  // [C,KPAD] fp16
    const float* __restrict__ gamma_,
    const float* __restrict__ beta_,
    const float* __restrict__ rmean,
    const float* __restrict__ rvar,
    float* __restrict__ out)          // [B,C,N]
{
    __shared__ _Float16 h_lds[COLS * LDH_];   // [col][r], r = GEMM-K (channel)
    __shared__ float s_dp[3][COLS];
    __shared__ int   s_idx[COLS];
    __shared__ float s_inv[C_], s_bias[C_], s_invd[32];
    __shared__ float s_out[C_ * PTS];

    const int tid = threadIdx.x;
    const int bn0 = blockIdx.x * PTS;       // global point base
    const int b   = bn0 >> 12;
    const int n0  = bn0 & (N_ - 1);

    // ---- init: BN affine + frequency table ----
    if (tid < C_) {
        const float inv = gamma_[tid] * rsqrtf(rvar[tid] + 1e-5f);
        s_inv[tid]  = inv;
        s_bias[tid] = beta_[tid] - rmean[tid] * inv;
    }
    if (tid < 32) {
        // 500^(-f/32) = exp2(-f * log2(500)/32)
        s_invd[tid] = exp2f(-(float)tid * 0.2801808715263400f);
    }

    // ---- Phase A: neighbor ids + relative coords (fp32) ----
    if (tid < COLS) {
        const int pt = tid >> 5;
        const int k  = tid & 31;
        const int gp = bn0 + pt;                    // b*N + n
        const int j  = idx[gp * K_ + k];
        s_idx[tid] = j;
        const float* pj = p + (size_t)(b * N_ + j) * 3;
        const float* pn = p + (size_t)gp * 3;
#pragma unroll
        for (int d = 0; d < 3; ++d) s_dp[d][tid] = pj[d] - pn[d];
        (void)k;
    }
    __syncthreads();

    // ---- Phase B: build h tile [col][0..223] fp16 in LDS ----
    // rows 0..2 = dp, rows 3..194 = pe*(xj+1), rows 195..223 = 0
    {
        const float* xb = x + (size_t)b * C_ * N_;
        for (int t = tid; t < COLS * (KPAD / 4); t += 256) {
            const int col = t / 56;              // 56 groups of 4 rows
            const int rg  = t - col * 56;
            const int r0  = rg * 4;
            const int j   = s_idx[col];
            half4 v;
#pragma unroll
            for (int jj = 0; jj < 4; ++jj) {
                const int r = r0 + jj;
                float val;
                if (r < 3) {
                    val = s_dp[r][col];
                } else if (r < CH_) {
                    const int c   = r - 3;
                    const int d   = c >> 6;
                    const int rem = c & 63;
                    const int f   = rem & 31;
                    const float ang = 50.0f * s_dp[d][col] * s_invd[f];
                    const float pe  = (rem < 32) ? __sinf(ang) : __cosf(ang);
                    const float xj  = xb[(size_t)c * N_ + j];
                    val = pe * (xj + 1.0f);
                } else {
                    val = 0.0f;
                }
                v[jj] = (_Float16)val;
            }
            *(half4*)(&h_lds[col * LDH_ + r0]) = v;  // 8B LDS write
        }
    }
    __syncthreads();

    // ---- Phase C: MFMA GEMM  y[192 x 128] = Wp[192 x 224] * h[224 x 128] ----
    const int lane = tid & 63;
    const int wave = tid >> 6;       // wave handles M-tiles wave*3 .. wave*3+2
    const int l15  = lane & 15;
    const int quad = lane >> 4;

    f32x4 acc[3][8];
#pragma unroll
    for (int i = 0; i < 3; ++i)
#pragma unroll
        for (int nt = 0; nt < 8; ++nt) acc[i][nt] = (f32x4)0.0f;

    for (int kt = 0; kt < 7; ++kt) {
        const int k0 = kt * 32 + quad * 8;
        half8 a[3], bf[8];
#pragma unroll
        for (int i = 0; i < 3; ++i) {
            const int m = (wave * 3 + i) * 16 + l15;
            a[i] = *(const half8*)(Wp + (size_t)m * KPAD + k0);    // global, L2-hot
        }
#pragma unroll
        for (int nt = 0; nt < 8; ++nt) {
            const int col = nt * 16 + l15;
            bf[nt] = *(const half8*)(&h_lds[col * LDH_ + k0]);     // ds_read_b128
        }
#pragma unroll
        for (int i = 0; i < 3; ++i)
#pragma unroll
            for (int nt = 0; nt < 8; ++nt)
                acc[i][nt] = __builtin_amdgcn_mfma_f32_16x16x32_f16(a[i], bf[nt], acc[i][nt], 0, 0, 0);
    }

    // ---- Epilogue: BN affine -> max over 32 neighbors -> ReLU -> s_out ----
    // C/D layout: col = lane&15, row = quad*4 + reg
#pragma unroll
    for (int i = 0; i < 3; ++i) {
        const int mbase = (wave * 3 + i) * 16 + quad * 4;
#pragma unroll
        for (int pt = 0; pt < PTS; ++pt) {
            const f32x4 va = acc[i][2 * pt];
            const f32x4 vb = acc[i][2 * pt + 1];
#pragma unroll
            for (int r = 0; r < 4; ++r) {
                const int m = mbase + r;
                const float inv = s_inv[m];
                const float bia = s_bias[m];
                float v = fmaxf(fmaf(va[r], inv, bia), fmaf(vb[r], inv, bia));
                v = fmaxf(v, __shfl_xor(v, 1));
                v = fmaxf(v, __shfl_xor(v, 2));
                v = fmaxf(v, __shfl_xor(v, 4));
                v = fmaxf(v, __shfl_xor(v, 8));
                if (l15 == 0) s_out[m * PTS + pt] = fmaxf(v, 0.0f);
            }
        }
    }
    __syncthreads();

    // ---- coalesced store: 4 consecutive n per row ----
    if (tid < C_) {
        const float4 o4 = *(const float4*)(&s_out[tid * PTS]);
        *(float4*)(&out[((size_t)b * C_ + tid) * N_ + n0]) = o4;
    }
}

extern "C" void kernel_launch(void* const* d_in, const int* in_sizes, int n_in,
                              void* d_out, int out_size, void* d_ws, size_t ws_size,
                              hipStream_t stream) {
    (void)in_sizes; (void)n_in; (void)out_size; (void)ws_size;
    const float* p      = (const float*)d_in[0];
    const float* x      = (const float*)d_in[1];
    const int*   idx    = (const int*)d_in[2];
    const float* W      = (const float*)d_in[3];
    const float* gamma_ = (const float*)d_in[4];
    const float* beta_  = (const float*)d_in[5];
    const float* rmean  = (const float*)d_in[6];
    const float* rvar   = (const float*)d_in[7];
    float* out = (float*)d_out;

    _Float16* Wp = (_Float16*)d_ws;   // needs 192*224*2 = 86016 B

    prep_w<<<(C_ * KPAD + 255) / 256, 256, 0, stream>>>(W, Wp);
    la_mfma<<<(B_ * N_) / PTS, 256, 0, stream>>>(p, x, idx, Wp,
                                                 gamma_, beta_, rmean, rvar, out);
}

// Round 3
// 446.748 us; speedup vs baseline: 2.8435x; 1.2418x over previous
//
#include <hip/hip_runtime.h>
#include <math.h>

// Problem constants
#define B_   4
#define N_   4096
#define K_   32
#define C_   192
#define CH_  195          // C + 3 (GEMM K-dim, zero-padded to KPAD)
#define KPAD 224          // 7 x 32
#define PTS  2            // points per block
#define COLS 64           // PTS * K_  (GEMM N-dim per block)
#define NKT  7            // K-tiles (KPAD/32)
#define NNT  4            // N-tiles (COLS/16)
#define GRID ((B_ * N_) / PTS)   // 8192 blocks

using half8 = __attribute__((ext_vector_type(8))) _Float16;
using f32x4 = __attribute__((ext_vector_type(4))) float;

// ---- per-launch W -> fp16 padded [192][224], pad cols zeroed ----
__global__ __launch_bounds__(256) void prep_w(const float* __restrict__ W,
                                              _Float16* __restrict__ Wp) {
    int i = blockIdx.x * 256 + threadIdx.x;
    if (i < C_ * KPAD) {
        int o = i / KPAD, c = i - o * KPAD;
        Wp[i] = (c < CH_) ? (_Float16)W[o * CH_ + c] : (_Float16)0.0f;
    }
}

// One block = 2 points, 256 threads (4 waves).
// h tile stored in LDS in MFMA B-fragment order:
//   element h[r][col]  (r = kt*32 + kq*8 + j, col = nt*16 + lsl)
//   lives at hb[((kt*4 + nt)*64 + kq*16 + lsl)*8 + j]
// -> Phase-B writes are wave-wide conflict-free ds_write_b128,
//    Phase-C b-frag reads are lane-contiguous conflict-free ds_read_b128.
__global__ __launch_bounds__(256, 4) void la_mfma(
    const float* __restrict__ p,      // [B,N,3]
    const float* __restrict__ x,      // [B,C,N]
    const int*   __restrict__ idx,    // [B,N,K]
    const _Float16* __restrict__ Wp,  // [C,KPAD] fp16
    const float* __restrict__ gamma_,
    const float* __restrict__ beta_,
    const float* __restrict__ rmean,
    const float* __restrict__ rvar,
    float* __restrict__ out)          // [B,C,N]
{
    __shared__ _Float16 hb[NKT * NNT * 64 * 8];   // 28672 B
    __shared__ float s_inv[C_], s_bias[C_], s_invd[32];
    __shared__ float s_out[C_ * PTS];

    const int tid  = threadIdx.x;
    const int lane = tid & 63;
    const int w    = tid >> 6;

    // XCD swizzle: physical blockIdx%8 = XCD -> contiguous logical range,
    // so each XCD's x-gathers stay inside ONE batch's 3 MB slice (L2-resident).
    const int q  = blockIdx.x & 7;
    const int sI = blockIdx.x >> 3;
    const int L  = q * (GRID / 8) + sI;
    const int bn0 = L * PTS;            // b*N + n0
    const int b   = bn0 >> 12;
    const int n0  = bn0 & (N_ - 1);

    // ---- init: BN affine + frequency table ----
    if (tid < C_) {
        const float inv = gamma_[tid] * rsqrtf(rvar[tid] + 1e-5f);
        s_inv[tid]  = inv;
        s_bias[tid] = beta_[tid] - rmean[tid] * inv;
    }
    if (tid < 32) s_invd[tid] = exp2f(-(float)tid * 0.2801808715263400f); // 500^(-f/32)
    __syncthreads();

    // ---- Phase B: build h tile, fragment-ordered ----
    const int col = lane;          // one column per lane; 4 waves split K-rows
    const int nt  = col >> 4;
    const int lsl = col & 15;
    {
        const int pt = col >> 5;
        const int k  = col & 31;
        const int gp = bn0 + pt;
        const int j  = idx[(size_t)gp * K_ + k];
        const float d0 = p[(size_t)(b * N_ + j) * 3 + 0] - p[(size_t)gp * 3 + 0];
        const float d1 = p[(size_t)(b * N_ + j) * 3 + 1] - p[(size_t)gp * 3 + 1];
        const float d2 = p[(size_t)(b * N_ + j) * 3 + 2] - p[(size_t)gp * 3 + 2];
        const float* xb = x + (size_t)b * C_ * N_ + j;   // gather base (lane-varying j)

#pragma unroll
        for (int i = 0; i < 7; ++i) {
            const int cb = w + 4 * i;      // 28 (kt,kq) combos split across 4 waves
            const int kt = cb >> 2;
            const int kq = cb & 3;
            const int rbase = kt * 32 + kq * 8;
            half8 v;
#pragma unroll
            for (int jj = 0; jj < 8; ++jj) {
                const int r = rbase + jj;   // wave-uniform -> no divergence
                float val;
                if (r >= CH_) {
                    val = 0.0f;
                } else if (r < 3) {
                    val = (r == 0) ? d0 : ((r == 1) ? d1 : d2);
                } else {
                    const int c = r - 3;
                    const float dd = (c < 64) ? d0 : ((c < 128) ? d1 : d2);
                    const float ang = 50.0f * dd * s_invd[c & 31];
                    const float pe  = ((c & 63) < 32) ? __sinf(ang) : __cosf(ang);
                    const float xj  = xb[(size_t)c * N_];
                    val = pe * (xj + 1.0f);
                }
                v[jj] = (_Float16)val;
            }
            *(half8*)(&hb[(size_t)(((kt * NNT + nt) * 64) + kq * 16 + lsl) * 8]) = v;
        }
    }
    __syncthreads();

    // ---- Phase C: MFMA GEMM  y[192 x 64] = Wp[192 x 224] * h[224 x 64] ----
    const int l15  = lane & 15;
    const int quad = lane >> 4;

    f32x4 acc[3][4];
#pragma unroll
    for (int i = 0; i < 3; ++i)
#pragma unroll
        for (int t = 0; t < 4; ++t) acc[i][t] = (f32x4)0.0f;

#pragma unroll
    for (int kt = 0; kt < 7; ++kt) {
        const int k0 = kt * 32 + quad * 8;
        half8 a[3], bf[4];
#pragma unroll
        for (int i = 0; i < 3; ++i) {
            const int m = (w * 3 + i) * 16 + l15;
            a[i] = *(const half8*)(Wp + (size_t)m * KPAD + k0);    // global, L2-hot
        }
#pragma unroll
        for (int t = 0; t < 4; ++t)
            bf[t] = *(const half8*)(&hb[(size_t)((kt * NNT + t) * 64 + lane) * 8]);
#pragma unroll
        for (int i = 0; i < 3; ++i)
#pragma unroll
            for (int t = 0; t < 4; ++t)
                acc[i][t] = __builtin_amdgcn_mfma_f32_16x16x32_f16(a[i], bf[t], acc[i][t], 0, 0, 0);
    }

    // ---- Epilogue: BN affine -> max over 32 neighbors -> ReLU ----
    // C/D layout: col = lane&15, row = quad*4 + reg
#pragma unroll
    for (int i = 0; i < 3; ++i) {
        const int mbase = (w * 3 + i) * 16 + quad * 4;
#pragma unroll
        for (int pt = 0; pt < PTS; ++pt) {
            const f32x4 va = acc[i][2 * pt];
            const f32x4 vb = acc[i][2 * pt + 1];
#pragma unroll
            for (int r = 0; r < 4; ++r) {
                const int m = mbase + r;
                const float inv = s_inv[m];
                const float bia = s_bias[m];
                float v = fmaxf(fmaf(va[r], inv, bia), fmaf(vb[r], inv, bia));
                v = fmaxf(v, __shfl_xor(v, 1));
                v = fmaxf(v, __shfl_xor(v, 2));
                v = fmaxf(v, __shfl_xor(v, 4));
                v = fmaxf(v, __shfl_xor(v, 8));
                if (l15 == 0) s_out[m * PTS + pt] = fmaxf(v, 0.0f);
            }
        }
    }
    __syncthreads();

    // ---- coalesced store: 2 consecutive n per channel row ----
    if (tid < C_) {
        const float2 o2 = *(const float2*)(&s_out[tid * PTS]);
        *(float2*)(&out[((size_t)b * C_ + tid) * N_ + n0]) = o2;
    }
}

extern "C" void kernel_launch(void* const* d_in, const int* in_sizes, int n_in,
                              void* d_out, int out_size, void* d_ws, size_t ws_size,
                              hipStream_t stream) {
    (void)in_sizes; (void)n_in; (void)out_size; (void)ws_size;
    const float* p      = (const float*)d_in[0];
    const float* x      = (const float*)d_in[1];
    const int*   idx    = (const int*)d_in[2];
    const float* W      = (const float*)d_in[3];
    const float* gamma_ = (const float*)d_in[4];
    const float* beta_  = (const float*)d_in[5];
    const float* rmean  = (const float*)d_in[6];
    const float* rvar   = (const float*)d_in[7];
    float* out = (float*)d_out;

    _Float16* Wp = (_Float16*)d_ws;   // 192*224*2 = 86016 B

    prep_w<<<(C_ * KPAD + 255) / 256, 256, 0, stream>>>(W, Wp);
    la_mfma<<<GRID, 256, 0, stream>>>(p, x, idx, Wp,
                                      gamma_, beta_, rmean, rvar, out);
}

// Round 5
// 174.934 us; speedup vs baseline: 7.2618x; 2.5538x over previous
//
#include <hip/hip_runtime.h>
#include <math.h>

// Problem constants
#define B_   4
#define N_   4096
#define K_   32
#define C_   192
#define CH_  195          // C + 3 (logical GEMM K)
#define KPAD 224          // 7 x 32 ; row map: r0..2=dp, r3..7=0, r8..199=channels, r200..223=0
#define PTS  2            // points per block
#define NKT  7            // K-tiles
#define NNT  4            // N-tiles (64 cols / 16)
#define GRID ((B_ * N_) / PTS)   // 8192 blocks

using half8 = __attribute__((ext_vector_type(8))) _Float16;
using f32x4 = __attribute__((ext_vector_type(4))) float;

// Module-static device scratch — NOT d_ws (R4 post-mortem: writing 6.4 MB of
// xT into d_ws overran the harness allocation and corrupted adjacent buffers;
// ws_size is only proven >= 86 KB). These are allocated at module load, never
// poisoned by the harness, and fully rewritten on every call.
__device__ _Float16 g_Wp[C_ * KPAD];                    // 86016 B
__device__ _Float16 g_xT[(size_t)B_ * N_ * C_];         // 6291456 B

// ---- W -> fp16 [192][224] with remapped K rows ----
__global__ __launch_bounds__(256) void prep_w(const float* __restrict__ W) {
    int i = blockIdx.x * 256 + threadIdx.x;
    if (i < C_ * KPAD) {
        int o = i / KPAD, r = i - o * KPAD;
        float v = 0.0f;
        if (r < 3)                  v = W[o * CH_ + r];            // dp part
        else if (r >= 8 && r < 200) v = W[o * CH_ + 3 + (r - 8)];  // channel part
        g_Wp[i] = (_Float16)v;
    }
}

// ---- x [B,C,N] f32 -> g_xT [B,N,C] fp16 (tiled transpose) ----
__global__ __launch_bounds__(256) void prep_xt(const float* __restrict__ x) {
    __shared__ float s[64][193];   // [n][c], pad breaks bank patterns
    const int tid = threadIdx.x;
    const int b   = blockIdx.y;
    const int n0  = blockIdx.x * 64;
    // load: coalesced float4 along n
#pragma unroll
    for (int i = 0; i < 12; ++i) {
        const int c = i * 16 + (tid >> 4);
        const int n = (tid & 15) * 4;
        const float4 v = *(const float4*)(x + ((size_t)b * C_ + c) * N_ + n0 + n);
        s[n + 0][c] = v.x; s[n + 1][c] = v.y; s[n + 2][c] = v.z; s[n + 3][c] = v.w;
    }
    __syncthreads();
    // store: half8 along c, 4 lanes cover 64 B of one row
    const int n = tid >> 2;
#pragma unroll
    for (int i = 0; i < 6; ++i) {
        const int ch = (tid & 3) + 4 * i;
        half8 v;
#pragma unroll
        for (int jj = 0; jj < 8; ++jj) v[jj] = (_Float16)s[n][ch * 8 + jj];
        *(half8*)(g_xT + ((size_t)b * N_ + n0 + n) * C_ + ch * 8) = v;
    }
}

// ---- main fused kernel: one block = 2 points, 256 threads ----
__global__ __launch_bounds__(256, 4) void la_mfma(
    const float* __restrict__ p,      // [B,N,3]
    const int*   __restrict__ idx,    // [B,N,K]
    const float* __restrict__ gamma_,
    const float* __restrict__ beta_,
    const float* __restrict__ rmean,
    const float* __restrict__ rvar,
    float* __restrict__ out)          // [B,C,N]
{
    __shared__ _Float16 hb[NKT * NNT * 64 * 8];   // 28672 B, B-fragment order
    __shared__ float s_inv[C_], s_bias[C_], s_invd[32];
    __shared__ float s_out[C_ * PTS];

    const int tid  = threadIdx.x;
    const int lane = tid & 63;
    const int w    = tid >> 6;

    // XCD swizzle: keep each XCD inside one batch's xT slice (L2-resident)
    const int q  = blockIdx.x & 7;
    const int sI = blockIdx.x >> 3;
    const int L  = q * (GRID / 8) + sI;
    const int bn0 = L * PTS;
    const int b   = bn0 >> 12;
    const int n0  = bn0 & (N_ - 1);

    if (tid < C_) {
        const float inv = gamma_[tid] * rsqrtf(rvar[tid] + 1e-5f);
        s_inv[tid]  = inv;
        s_bias[tid] = beta_[tid] - rmean[tid] * inv;
    }
    if (tid < 32) s_invd[tid] = exp2f(-(float)tid * 0.2801808715263400f); // 500^(-f/32)
    __syncthreads();

    // ---- Phase B: 4 threads per column; coalesced half8 gathers from g_xT ----
    {
        const int col = tid >> 2;      // 0..63
        const int q0  = tid & 3;
        const int nt  = col >> 4;
        const int lsl = col & 15;
        const int pt  = col >> 5;
        const int k   = col & 31;
        const int gp  = bn0 + pt;
        const int j   = idx[(size_t)gp * K_ + k];
        float d0 = p[(size_t)(b * N_ + j) * 3 + 0] - p[(size_t)gp * 3 + 0];
        float d1 = p[(size_t)(b * N_ + j) * 3 + 1] - p[(size_t)gp * 3 + 1];
        float d2 = p[(size_t)(b * N_ + j) * 3 + 2] - p[(size_t)gp * 3 + 2];
        const _Float16* xh = g_xT + ((size_t)b * N_ + j) * C_;

#pragma unroll
        for (int i = 0; i < 6; ++i) {
            const int chunk = q0 + 4 * i;           // 0..23
            const half8 v = *(const half8*)(xh + chunk * 8);
            half8 hv;
#pragma unroll
            for (int jj = 0; jj < 8; ++jj) {
                const int c = chunk * 8 + jj;
                const float dd = (c < 64) ? d0 : ((c < 128) ? d1 : d2);
                // cos(a) = sin(a + pi/2): no divergent dual transcendental path
                const float ang = 50.0f * dd * s_invd[c & 31]
                                + (((c & 63) < 32) ? 0.0f : 1.5707963f);
                const float pe = __sinf(ang);
                hv[jj] = (_Float16)(pe * ((float)v[jj] + 1.0f));
            }
            const int ro = chunk + 1;               // rows 8..199 -> octets 1..24
            const int kt = ro >> 2, kq = ro & 3;
            *(half8*)(&hb[(size_t)((kt * NNT + nt) * 64 + kq * 16 + lsl) * 8]) = hv;
        }
        if (q0 == 0) {          // octet 0: dp rows + zero pad
            half8 hv = (half8)(_Float16)0.0f;
            hv[0] = (_Float16)d0; hv[1] = (_Float16)d1; hv[2] = (_Float16)d2;
            *(half8*)(&hb[(size_t)((0 * NNT + nt) * 64 + 0 * 16 + lsl) * 8]) = hv;
        } else {                // octets 25..27: zeros
            const int ro = 24 + q0;
            const int kt = ro >> 2, kq = ro & 3;
            *(half8*)(&hb[(size_t)((kt * NNT + nt) * 64 + kq * 16 + lsl) * 8]) = (half8)(_Float16)0.0f;
        }
    }
    __syncthreads();

    // ---- Phase C: MFMA GEMM  y[192 x 64] = Wp[192 x 224] * h[224 x 64] ----
    const int l15  = lane & 15;
    const int quad = lane >> 4;

    f32x4 acc[3][4];
#pragma unroll
    for (int i = 0; i < 3; ++i)
#pragma unroll
        for (int t = 0; t < 4; ++t) acc[i][t] = (f32x4)0.0f;

#pragma unroll
    for (int kt = 0; kt < 7; ++kt) {
        const int k0 = kt * 32 + quad * 8;
        half8 a[3], bf[4];
#pragma unroll
        for (int i = 0; i < 3; ++i) {
            const int m = (w * 3 + i) * 16 + l15;
            a[i] = *(const half8*)(g_Wp + (size_t)m * KPAD + k0);   // L1/L2-hot
        }
#pragma unroll
        for (int t = 0; t < 4; ++t)
            bf[t] = *(const half8*)(&hb[(size_t)((kt * NNT + t) * 64 + lane) * 8]);
#pragma unroll
        for (int i = 0; i < 3; ++i)
#pragma unroll
            for (int t = 0; t < 4; ++t)
                acc[i][t] = __builtin_amdgcn_mfma_f32_16x16x32_f16(a[i], bf[t], acc[i][t], 0, 0, 0);
    }

    // ---- Epilogue: BN affine -> max over 32 neighbors -> ReLU ----
    // C/D layout: col = lane&15, row = quad*4 + reg
#pragma unroll
    for (int i = 0; i < 3; ++i) {
        const int mbase = (w * 3 + i) * 16 + quad * 4;
#pragma unroll
        for (int pt = 0; pt < PTS; ++pt) {
            const f32x4 va = acc[i][2 * pt];
            const f32x4 vb = acc[i][2 * pt + 1];
#pragma unroll
            for (int r = 0; r < 4; ++r) {
                const int m = mbase + r;
                const float inv = s_inv[m];
                const float bia = s_bias[m];
                float v = fmaxf(fmaf(va[r], inv, bia), fmaf(vb[r], inv, bia));
                v = fmaxf(v, __shfl_xor(v, 1));
                v = fmaxf(v, __shfl_xor(v, 2));
                v = fmaxf(v, __shfl_xor(v, 4));
                v = fmaxf(v, __shfl_xor(v, 8));
                if (l15 == 0) s_out[m * PTS + pt] = fmaxf(v, 0.0f);
            }
        }
    }
    __syncthreads();

    if (tid < C_) {
        const float2 o2 = *(const float2*)(&s_out[tid * PTS]);
        *(float2*)(&out[((size_t)b * C_ + tid) * N_ + n0]) = o2;
    }
}

extern "C" void kernel_launch(void* const* d_in, const int* in_sizes, int n_in,
                              void* d_out, int out_size, void* d_ws, size_t ws_size,
                              hipStream_t stream) {
    (void)in_sizes; (void)n_in; (void)out_size; (void)d_ws; (void)ws_size;
    const float* p      = (const float*)d_in[0];
    const float* x      = (const float*)d_in[1];
    const int*   idx    = (const int*)d_in[2];
    const float* W      = (const float*)d_in[3];
    const float* gamma_ = (const float*)d_in[4];
    const float* beta_  = (const float*)d_in[5];
    const float* rmean  = (const float*)d_in[6];
    const float* rvar   = (const float*)d_in[7];
    float* out = (float*)d_out;

    prep_w<<<(C_ * KPAD + 255) / 256, 256, 0, stream>>>(W);
    prep_xt<<<dim3(N_ / 64, B_), 256, 0, stream>>>(x);
    la_mfma<<<GRID, 256, 0, stream>>>(p, idx, gamma_, beta_, rmean, rvar, out);
}

// Round 7
// 173.036 us; speedup vs baseline: 7.3415x; 1.0110x over previous
//
#include <hip/hip_runtime.h>
#include <math.h>

// Problem constants
#define B_   4
#define N_   4096
#define K_   32
#define C_   192
#define CH_  195          // C + 3 (logical GEMM K)
#define KPAD 224          // 7 x 32 ; rows: 0..2=dp, 3..7=0, 8..199=channels, 200..223=0
#define PTS  2            // points per block
#define NKT  7            // K-tiles
#define NNT  4            // N-tiles (64 cols / 16)
#define GRID ((B_ * N_) / PTS)   // 8192 blocks

using half8  = __attribute__((ext_vector_type(8))) _Float16;
using half2v = __attribute__((ext_vector_type(2))) _Float16;
using f32x4  = __attribute__((ext_vector_type(4))) float;

// Module-static device scratch (NOT d_ws — R4 post-mortem: overran ws_size).
__device__ _Float16 g_Wp[C_ * KPAD];                    // 86016 B
__device__ _Float16 g_xT[(size_t)B_ * N_ * C_];         // 6291456 B

// 16-lane max reduction on the VALU via DPP (no DS pipe, no lgkm waits)
__device__ __forceinline__ float dpp_max16(float v) {
    // quad_perm [1,0,3,2] (xor1), quad_perm [2,3,0,1] (xor2),
    // row_half_mirror (joins quads within 8), row_mirror (joins 8s within 16)
    int s;
    s = __builtin_amdgcn_update_dpp(0, __float_as_int(v), 0xB1,  0xF, 0xF, true);
    v = fmaxf(v, __int_as_float(s));
    s = __builtin_amdgcn_update_dpp(0, __float_as_int(v), 0x4E,  0xF, 0xF, true);
    v = fmaxf(v, __int_as_float(s));
    s = __builtin_amdgcn_update_dpp(0, __float_as_int(v), 0x141, 0xF, 0xF, true);
    v = fmaxf(v, __int_as_float(s));
    s = __builtin_amdgcn_update_dpp(0, __float_as_int(v), 0x140, 0xF, 0xF, true);
    v = fmaxf(v, __int_as_float(s));
    return v;
}

// ---- W -> fp16 [192][224] with remapped K rows ----
__global__ __launch_bounds__(256) void prep_w(const float* __restrict__ W) {
    int i = blockIdx.x * 256 + threadIdx.x;
    if (i < C_ * KPAD) {
        int o = i / KPAD, r = i - o * KPAD;
        float v = 0.0f;
        if (r < 3)                  v = W[o * CH_ + r];            // dp part
        else if (r >= 8 && r < 200) v = W[o * CH_ + 3 + (r - 8)];  // channel part
        g_Wp[i] = (_Float16)v;
    }
}

// ---- x [B,C,N] f32 -> g_xT [B,N,C] fp16 ; 32n x 96c tiles, 1024 blocks ----
__global__ __launch_bounds__(256) void prep_xt(const float* __restrict__ x) {
    __shared__ float s[32][97];    // [n][c_local]; 97: write phase 2-way banks (free)
    const int tid = threadIdx.x;
    const int b   = blockIdx.z;
    const int c0  = blockIdx.y * 96;
    const int n0  = blockIdx.x * 32;
#pragma unroll
    for (int it = 0; it < 3; ++it) {
        const int c  = it * 32 + (tid >> 3);        // 0..95
        const int n4 = (tid & 7) * 4;
        const float4 v = *(const float4*)(x + ((size_t)b * C_ + c0 + c) * N_ + n0 + n4);
        s[n4 + 0][c] = v.x; s[n4 + 1][c] = v.y; s[n4 + 2][c] = v.z; s[n4 + 3][c] = v.w;
    }
    __syncthreads();
#pragma unroll
    for (int it = 0; it < 2; ++it) {
        const int t = it * 256 + tid;               // 0..383 used
        if (t < 32 * 12) {
            const int n  = t / 12;
            const int ch = t - n * 12;
            half8 v;
#pragma unroll
            for (int jj = 0; jj < 8; ++jj) v[jj] = (_Float16)s[n][ch * 8 + jj];
            *(half8*)(g_xT + ((size_t)b * N_ + n0 + n) * C_ + c0 + ch * 8) = v;
        }
    }
}

// ---- main fused kernel: one block = 2 points, 256 threads ----
__global__ __launch_bounds__(256, 4) void la_mfma(
    const float* __restrict__ p,      // [B,N,3]
    const int*   __restrict__ idx,    // [B,N,K]
    const float* __restrict__ gamma_,
    const float* __restrict__ beta_,
    const float* __restrict__ rmean,
    const float* __restrict__ rvar,
    float* __restrict__ out)          // [B,C,N]
{
    __shared__ _Float16 hb[NKT * NNT * 64 * 8];   // 28672 B; s_out unioned after Phase C
    __shared__ float s_inv[C_], s_bias[C_], s_fr[32];

    const int tid  = threadIdx.x;
    const int lane = tid & 63;
    const int w    = tid >> 6;

    // XCD swizzle: keep each XCD inside one batch's xT slice (L2-resident)
    const int q  = blockIdx.x & 7;
    const int sI = blockIdx.x >> 3;
    const int L  = q * (GRID / 8) + sI;
    const int bn0 = L * PTS;
    const int b   = bn0 >> 12;
    const int n0  = bn0 & (N_ - 1);

    if (tid < C_) {
        const float inv = gamma_[tid] * rsqrtf(rvar[tid] + 1e-5f);
        s_inv[tid]  = inv;
        s_bias[tid] = beta_[tid] - rmean[tid] * inv;
    }
    // s_fr[f] = (50 / 2pi) * 500^(-f/32)  (v_sin takes revolutions)
    if (tid < 32) s_fr[tid] = 7.9577471546e0f * exp2f(-(float)tid * 0.2801808715263400f);
    __syncthreads();

    // ---- Phase B: conflict-free mapping: q0 = lane>>4, col = w*16 + (lane&15) ----
    {
        const int lsl = lane & 15;
        const int q0  = lane >> 4;
        const int col = w * 16 + lsl;     // n-tile nt = w
        const int pt  = col >> 5;         // = w>>1
        const int k   = col & 31;
        const int gp  = bn0 + pt;
        const int j   = idx[(size_t)gp * K_ + k];
        const float d0 = p[(size_t)(b * N_ + j) * 3 + 0] - p[(size_t)gp * 3 + 0];
        const float d1 = p[(size_t)(b * N_ + j) * 3 + 1] - p[(size_t)gp * 3 + 1];
        const float d2 = p[(size_t)(b * N_ + j) * 3 + 2] - p[(size_t)gp * 3 + 2];
        const _Float16* xh = g_xT + ((size_t)b * N_ + j) * C_;

        // per-thread frequency set is chunk-invariant: f = q0*8 + jj
        float sfr[8];
#pragma unroll
        for (int jj = 0; jj < 8; ++jj) sfr[jj] = s_fr[q0 * 8 + jj];

#pragma unroll
        for (int i = 0; i < 6; ++i) {
            const int chunk = q0 + 4 * i;           // 0..23
            const half8 v = *(const half8*)(xh + chunk * 8);
            const float dd  = (chunk < 8) ? d0 : ((chunk < 16) ? d1 : d2);
            const float off = (chunk & 4) ? 0.25f : 0.0f;   // cos = sin(+1/4 rev)
            half8 hv;
#pragma unroll
            for (int jj = 0; jj < 8; jj += 2) {
                const float pe0 = __builtin_amdgcn_sinf(fmaf(dd, sfr[jj],     off));
                const float pe1 = __builtin_amdgcn_sinf(fmaf(dd, sfr[jj + 1], off));
                const half2v pe2 = __builtin_bit_cast(half2v, __builtin_amdgcn_cvt_pkrtz(pe0, pe1));
                half2v v2; v2[0] = v[jj]; v2[1] = v[jj + 1];
                const half2v r2 = pe2 * v2 + pe2;   // v_pk_fma_f16: pe*(x+1)
                hv[jj] = r2[0]; hv[jj + 1] = r2[1];
            }
            const int ro = chunk + 1;               // channel octets 1..24
            const int kt = ro >> 2, kq = ro & 3;
            *(half8*)(&hb[(size_t)((kt * NNT + w) * 64 + kq * 16 + lsl) * 8]) = hv;
        }
        if (q0 == 0) {          // octet 0: dp rows 0..2 + zero rows 3..7
            half8 hv0 = (half8)(_Float16)0.0f;
            hv0[0] = (_Float16)d0; hv0[1] = (_Float16)d1; hv0[2] = (_Float16)d2;
            *(half8*)(&hb[(size_t)((0 * NNT + w) * 64 + 0 * 16 + lsl) * 8]) = hv0;
        } else {                // octets 25..27: zero rows 200..223
            const int ro = 24 + q0;
            const int kt = ro >> 2, kq = ro & 3;
            *(half8*)(&hb[(size_t)((kt * NNT + w) * 64 + kq * 16 + lsl) * 8]) = (half8)(_Float16)0.0f;
        }
    }
    __syncthreads();

    // ---- Phase C: MFMA GEMM  y[192 x 64] = Wp[192 x 224] * h[224 x 64] ----
    const int l15  = lane & 15;
    const int quad = lane >> 4;

    f32x4 acc[3][4];
#pragma unroll
    for (int i = 0; i < 3; ++i)
#pragma unroll
        for (int t = 0; t < 4; ++t) acc[i][t] = (f32x4)0.0f;

#pragma unroll
    for (int kt = 0; kt < 7; ++kt) {
        const int k0 = kt * 32 + quad * 8;
        half8 a[3], bf[4];
#pragma unroll
        for (int i = 0; i < 3; ++i) {
            const int m = (w * 3 + i) * 16 + l15;
            a[i] = *(const half8*)(g_Wp + (size_t)m * KPAD + k0);   // L1/L2-hot
        }
#pragma unroll
        for (int t = 0; t < 4; ++t)
            bf[t] = *(const half8*)(&hb[(size_t)((kt * NNT + t) * 64 + lane) * 8]);
#pragma unroll
        for (int i = 0; i < 3; ++i)
#pragma unroll
            for (int t = 0; t < 4; ++t)
                acc[i][t] = __builtin_amdgcn_mfma_f32_16x16x32_f16(a[i], bf[t], acc[i][t], 0, 0, 0);
    }

    __syncthreads();   // all hb reads complete -> safe to union s_out onto hb
    float* s_out = (float*)hb;

    // ---- Epilogue: BN affine -> max over 32 neighbors (DPP) -> ReLU ----
    // C/D layout: col = lane&15, row = quad*4 + reg
#pragma unroll
    for (int i = 0; i < 3; ++i) {
        const int mbase = (w * 3 + i) * 16 + quad * 4;
#pragma unroll
        for (int pt = 0; pt < PTS; ++pt) {
            const f32x4 va = acc[i][2 * pt];
            const f32x4 vb = acc[i][2 * pt + 1];
#pragma unroll
            for (int r = 0; r < 4; ++r) {
                const int m = mbase + r;
                const float inv = s_inv[m];
                const float bia = s_bias[m];
                float v = fmaxf(fmaf(va[r], inv, bia), fmaf(vb[r], inv, bia));
                v = dpp_max16(v);
                if (l15 == 0) s_out[m * PTS + pt] = fmaxf(v, 0.0f);
            }
        }
    }
    __syncthreads();

    if (tid < C_) {
        const float2 o2 = *(const float2*)(&s_out[tid * PTS]);
        *(float2*)(&out[((size_t)b * C_ + tid) * N_ + n0]) = o2;
    }
}

extern "C" void kernel_launch(void* const* d_in, const int* in_sizes, int n_in,
                              void* d_out, int out_size, void* d_ws, size_t ws_size,
                              hipStream_t stream) {
    (void)in_sizes; (void)n_in; (void)out_size; (void)d_ws; (void)ws_size;
    const float* p      = (const float*)d_in[0];
    const float* x      = (const float*)d_in[1];
    const int*   idx    = (const int*)d_in[2];
    const float* W      = (const float*)d_in[3];
    const float* gamma_ = (const float*)d_in[4];
    const float* beta_  = (const float*)d_in[5];
    const float* rmean  = (const float*)d_in[6];
    const float* rvar   = (const float*)d_in[7];
    float* out = (float*)d_out;

    prep_w<<<(C_ * KPAD + 255) / 256, 256, 0, stream>>>(W);
    prep_xt<<<dim3(N_ / 32, 2, B_), 256, 0, stream>>>(x);
    la_mfma<<<GRID, 256, 0, stream>>>(p, idx, gamma_, beta_, rmean, rvar, out);
}